// Round 2
// baseline (3567.929 us; speedup 1.0000x reference)
//
#include <hip/hip_runtime.h>
#include <stdint.h>

#define NITEMS 50000
#define SEQ    200
#define TMAX   199
#define NB     4

typedef float v2f __attribute__((ext_vector_type(2)));
typedef unsigned long long u64;

// ws layout:
//   [0,     8192): flags, 64 batches * 32 ints (128B/batch)
//   [8192,  8200): accum {nll_sum, cnt}
//   [12288, 12288 + 64*2*256*4): h exchange buffer (batch, parity, 256)

template<int CTRL>
__device__ __forceinline__ float dpp_add(float x) {
    int r = __builtin_amdgcn_update_dpp(0, __float_as_int(x), CTRL, 0xF, 0xF, true);
    return x + __int_as_float(r);
}

__device__ __forceinline__ void ld_h2(const u64* p, float* d) {
    u64 a = __hip_atomic_load(p, __ATOMIC_RELAXED, __HIP_MEMORY_SCOPE_AGENT);
    union { u64 u; float f[2]; } c; c.u = a;
    d[0] = c.f[0]; d[1] = c.f[1];
}

__global__ __launch_bounds__(512, 2)
void lstm_main(const int* __restrict__ items, const int* __restrict__ actions,
               const float* __restrict__ WihT, const float* __restrict__ Whh,
               const float* __restrict__ b_lstm, const float* __restrict__ trans_emb,
               const float* __restrict__ Wq, const float* __restrict__ bq,
               int* flags, float* h_buf, float* accum)
{
    const int bid  = blockIdx.x;                 // 0..63
    const int q    = (bid >> 3) & 3;             // quarter 0..3
    const int g    = (bid & 7) + 8 * (bid >> 5); // group 0..15 (XCD co-location heuristic)
    const int g4   = g * 4;                      // first batch of group
    const int tid  = threadIdx.x;
    const int lane = tid & 63;
    const int wv   = tid >> 6;
    const int rg   = tid >> 4;    // 0..31 rowgroup (8 rows each)
    const int kc   = tid & 15;    // 0..15 k-chunk (16 k each)

    __shared__ float xp_lds[2][NB][256];
    __shared__ float gate_lds[NB][256];
    __shared__ float b_lds[256];
    __shared__ float emb_lds[2][NB][256];
    __shared__ float wq_lds[2][256];
    __shared__ float bq_s[2];
    __shared__ int   items_s[NB][SEQ];
    __shared__ int   act_s[NB][SEQ];
    __shared__ int   L_lds[NB];

    // ---------------- prologue ----------------
    for (int i = tid; i < NB * SEQ; i += 512) {
        const int jj = i / SEQ, pos = i - jj * SEQ;
        items_s[jj][pos] = items[(g4 + jj) * SEQ + pos];
        act_s[jj][pos]   = actions[(g4 + jj) * SEQ + pos];
    }
    if (tid < 256) {
        b_lds[tid] = b_lstm[(tid >> 6) * 256 + q * 64 + (tid & 63)];
    } else {
        const int k = tid - 256;
        wq_lds[0][k] = Wq[k];
        wq_lds[1][k] = Wq[256 + k];
    }
    if (tid == 0) { bq_s[0] = bq[0]; bq_s[1] = bq[1]; }
    __syncthreads();
    if (tid < NB) {
        int Lj = 0;
        while (Lj < SEQ && items_s[tid][Lj] != 0) ++Lj;   // valid region is a prefix
        L_lds[tid] = min(Lj, TMAX);
    }
    __syncthreads();
    int Lr[NB]; int Lmax = 0;
    #pragma unroll
    for (int jj = 0; jj < NB; ++jj) { Lr[jj] = L_lds[jj]; Lmax = max(Lmax, Lr[jj]); }

    // Whh slice into registers as float2-pairs along k:
    // thread (rg,kc) holds rows rg*8..+8, k in [16*kc, 16*kc+16)
    v2f wgt2[8][8];
    #pragma unroll
    for (int r = 0; r < 8; ++r) {
        const int r_blk = rg * 8 + r;                               // 0..255
        const int j = (r_blk >> 6) * 256 + q * 64 + (r_blk & 63);   // global gate row
        const float4* wp = (const float4*)(Whh + (size_t)j * 256 + kc * 16);
        #pragma unroll
        for (int m = 0; m < 4; ++m) {
            float4 v = wp[m];
            wgt2[r][2*m]   = (v2f){v.x, v.y};
            wgt2[r][2*m+1] = (v2f){v.z, v.w};
        }
    }

    // stage x_proj for t=0 (waves 1..4, one batch each)
    if (wv >= 1 && wv <= 4) {
        const int jj = wv - 1;
        const int it = items_s[jj][0], ac = act_s[jj][0];
        const int c = lane >> 4, off = (lane & 15) * 4;
        float4 va = *(const float4*)(WihT + (size_t)it * 1024 + c * 256 + q * 64 + off);
        float4 vb = *(const float4*)(WihT + (size_t)(NITEMS + ac) * 1024 + c * 256 + q * 64 + off);
        *(float4*)&xp_lds[0][jj][c * 64 + off] =
            make_float4(va.x+vb.x, va.y+vb.y, va.z+vb.z, va.w+vb.w);
    }
    __syncthreads();

    float c_cell[NB];
    #pragma unroll
    for (int jj = 0; jj < NB; ++jj) c_cell[jj] = 0.f;
    float nll_acc = 0.f, cnt_acc = 0.f;
    v2f hr2[NB][8];
    #pragma unroll
    for (int jj = 0; jj < NB; ++jj)
        #pragma unroll
        for (int m = 0; m < 8; ++m) hr2[jj][m] = (v2f){0.f, 0.f};

    for (int t = 0; t < Lmax; ++t) {
        // ---- phase A: poll (relaxed) + one acquire fence + h loads ----
        if (t > 0) {
            const int jjp = (lane >> 2) & 3, pp = lane & 3;
            const bool need = (lane < 16) && (pp != q) && (t < L_lds[jjp]);
            const int* fp = &flags[(g4 + jjp) * 32 + pp];
            int guard = 0;
            for (;;) {
                int v = need ? __hip_atomic_load(fp, __ATOMIC_RELAXED,
                                                 __HIP_MEMORY_SCOPE_AGENT)
                             : 0x7fffffff;
                if (__all(v >= t)) break;
                __builtin_amdgcn_s_sleep(1);
                if (++guard > (1 << 17)) break;   // bounded: never hang
            }
            __threadfence();   // one acquire fence for the round

            #pragma unroll
            for (int jj = 0; jj < NB; ++jj) {
                if (t < Lr[jj]) {
                    const u64* hp = (const u64*)(h_buf + (size_t)(g4 + jj) * 512
                                                 + (t & 1) * 256 + kc * 16);
                    #pragma unroll
                    for (int m = 0; m < 8; ++m) {
                        float d2[2];
                        ld_h2(hp + m, d2);
                        hr2[jj][m] = (v2f){d2[0], d2[1]};
                    }
                }
            }
        }

        // ---- early issues (consumed after B1) ----
        const int tn = t + 1;
        float4 xa, xb;
        float4 ev[NB];
        float  her[2][4];
        if (wv >= 1 && wv <= 4) {
            const int jj = wv - 1;
            if (tn < L_lds[jj]) {
                const int it = items_s[jj][tn], ac = act_s[jj][tn];
                const int c = lane >> 4, off = (lane & 15) * 4;
                xa = *(const float4*)(WihT + (size_t)it * 1024 + c * 256 + q * 64 + off);
                xb = *(const float4*)(WihT + (size_t)(NITEMS + ac) * 1024 + c * 256 + q * 64 + off);
            }
        } else if (wv == 5 && q == 0) {
            #pragma unroll
            for (int jj = 0; jj < NB; ++jj) {
                if (t < Lr[jj]) {
                    const int qe = items_s[jj][t + 1];
                    ev[jj] = make_float4(0.f, 0.f, 0.f, 0.f);
                    if (qe != 0)
                        ev[jj] = *(const float4*)(trans_emb + (size_t)qe * 256 + 4 * lane);
                }
            }
        } else if ((wv == 6 || wv == 7) && q == 0 && t > 0) {
            #pragma unroll
            for (int jb = 0; jb < 2; ++jb) {
                const int jj = ((wv - 6) << 1) + jb;
                if (t < L_lds[jj]) {
                    const u64* hp = (const u64*)(h_buf + (size_t)(g4 + jj) * 512
                                                 + (t & 1) * 256 + 4 * lane);
                    ld_h2(hp,     &her[jb][0]);
                    ld_h2(hp + 1, &her[jb][2]);
                }
            }
        }

        // ---- stage 2+3: partial dots (v_pk_fma_f32) + DPP 16-lane reduce ----
        #pragma unroll
        for (int jj = 0; jj < NB; ++jj) {
            if (t < Lr[jj]) {
                v2f acc2[8];
                #pragma unroll
                for (int r = 0; r < 8; ++r) acc2[r] = (v2f){0.f, 0.f};
                #pragma unroll
                for (int m = 0; m < 8; ++m)
                    #pragma unroll
                    for (int r = 0; r < 8; ++r)
                        acc2[r] = __builtin_elementwise_fma(wgt2[r][m], hr2[jj][m], acc2[r]);
                #pragma unroll
                for (int r = 0; r < 8; ++r) {
                    float v = acc2[r].x + acc2[r].y;
                    v = dpp_add<0x128>(v);   // row_ror:8
                    v = dpp_add<0x124>(v);   // row_ror:4
                    v = dpp_add<0x122>(v);   // row_ror:2
                    v = dpp_add<0x121>(v);   // row_ror:1
                    if (kc == 0) {
                        const int r_blk = rg * 8 + r;
                        gate_lds[jj][r_blk] = v + xp_lds[t & 1][jj][r_blk] + b_lds[r_blk];
                    }
                }
            }
        }
        __syncthreads();   // B1

        // ---- stage 4: per-wave roles ----
        if (tid < 64) {
            const int d = lane;
            #pragma unroll
            for (int jj = 0; jj < NB; ++jj) {
                if (t < Lr[jj]) {
                    float gi = gate_lds[jj][d];
                    float gf = gate_lds[jj][64 + d];
                    float gg = gate_lds[jj][128 + d];
                    float go = gate_lds[jj][192 + d];
                    float ii = 1.f / (1.f + __expf(-gi));
                    float ff = 1.f / (1.f + __expf(-gf));
                    float oo = 1.f / (1.f + __expf(-go));
                    float gt = tanhf(gg);
                    c_cell[jj] = ff * c_cell[jj] + ii * gt;
                    float hn = oo * tanhf(c_cell[jj]);
                    __hip_atomic_store(&h_buf[(size_t)(g4 + jj) * 512
                                              + ((t + 1) & 1) * 256 + q * 64 + d],
                                       hn, __ATOMIC_RELAXED, __HIP_MEMORY_SCOPE_AGENT);
                }
            }
            // one wave-wide release store covers all 4 flags (single vmcnt drain)
            if (lane < NB) {
                if (t < L_lds[lane])
                    __hip_atomic_store(&flags[(g4 + lane) * 32 + q], t + 1,
                                       __ATOMIC_RELEASE, __HIP_MEMORY_SCOPE_AGENT);
            }
        } else if (wv >= 1 && wv <= 4) {
            const int jj = wv - 1;
            if (tn < L_lds[jj]) {
                const int c = lane >> 4, off = (lane & 15) * 4;
                *(float4*)&xp_lds[tn & 1][jj][c * 64 + off] =
                    make_float4(xa.x+xb.x, xa.y+xb.y, xa.z+xb.z, xa.w+xb.w);
            }
        } else if (wv == 5 && q == 0) {
            #pragma unroll
            for (int jj = 0; jj < NB; ++jj) {
                if (t < Lr[jj])
                    *(float4*)&emb_lds[t & 1][jj][4 * lane] = ev[jj];
            }
        } else if ((wv == 6 || wv == 7) && q == 0 && t > 0) {
            #pragma unroll
            for (int jb = 0; jb < 2; ++jb) {
                const int jj = ((wv - 6) << 1) + jb;
                if (t < L_lds[jj]) {   // loss position t-1
                    const float* eb = &emb_lds[(t - 1) & 1][jj][0];
                    float s0 = 0.f, s1 = 0.f;
                    #pragma unroll
                    for (int m = 0; m < 4; ++m) {
                        const int k = 4 * lane + m;
                        float p = eb[k] * her[jb][m];
                        s0 = fmaf(p, wq_lds[0][k], s0);
                        s1 = fmaf(p, wq_lds[1][k], s1);
                    }
                    #pragma unroll
                    for (int off2 = 32; off2; off2 >>= 1) {
                        s0 += __shfl_xor(s0, off2);
                        s1 += __shfl_xor(s1, off2);
                    }
                    if (lane == 0) {
                        const int tgt = act_s[jj][t];
                        float z0 = s0 + bq_s[0], z1 = s1 + bq_s[1];
                        float mz = fmaxf(z0, z1);
                        float lse = mz + __logf(__expf(z0 - mz) + __expf(z1 - mz));
                        nll_acc += lse - (tgt ? z1 : z0);
                        cnt_acc += 1.f;
                    }
                }
            }
        }
        __syncthreads();   // B2
    }

    // ---- tails: position L-1 uses h^L, valid iff items[L] != 0 (len==200 case) ----
    if (q == 0 && (wv == 6 || wv == 7)) {
        #pragma unroll
        for (int jb = 0; jb < 2; ++jb) {
            const int jj = ((wv - 6) << 1) + jb;
            const int Lj = L_lds[jj];
            if (items_s[jj][Lj] != 0) {
                if (lane < 4) {
                    int guard = 0;
                    while (__hip_atomic_load(&flags[(g4 + jj) * 32 + lane],
                                             __ATOMIC_RELAXED,
                                             __HIP_MEMORY_SCOPE_AGENT) < Lj) {
                        __builtin_amdgcn_s_sleep(1);
                        if (++guard > (1 << 17)) break;
                    }
                }
                __threadfence();
                const u64* hp = (const u64*)(h_buf + (size_t)(g4 + jj) * 512
                                             + (Lj & 1) * 256 + 4 * lane);
                float he2[4];
                ld_h2(hp,     &he2[0]);
                ld_h2(hp + 1, &he2[2]);
                const float* eb = &emb_lds[(Lj - 1) & 1][jj][0];
                float s0 = 0.f, s1 = 0.f;
                #pragma unroll
                for (int m = 0; m < 4; ++m) {
                    const int k = 4 * lane + m;
                    float p = eb[k] * he2[m];
                    s0 = fmaf(p, wq_lds[0][k], s0);
                    s1 = fmaf(p, wq_lds[1][k], s1);
                }
                #pragma unroll
                for (int off2 = 32; off2; off2 >>= 1) {
                    s0 += __shfl_xor(s0, off2);
                    s1 += __shfl_xor(s1, off2);
                }
                if (lane == 0) {
                    const int tgt = act_s[jj][Lj];
                    float z0 = s0 + bq_s[0], z1 = s1 + bq_s[1];
                    float mz = fmaxf(z0, z1);
                    float lse = mz + __logf(__expf(z0 - mz) + __expf(z1 - mz));
                    nll_acc += lse - (tgt ? z1 : z0);
                    cnt_acc += 1.f;
                }
            }
        }
        if (lane == 0) {
            atomicAdd(&accum[0], nll_acc);
            atomicAdd(&accum[1], cnt_acc);
        }
    }
}

__global__ void finalize_k(const float* __restrict__ accum, float* __restrict__ out) {
    out[0] = accum[0] / accum[1];
}

extern "C" void kernel_launch(void* const* d_in, const int* in_sizes, int n_in,
                              void* d_out, int out_size, void* d_ws, size_t ws_size,
                              hipStream_t stream)
{
    const int*   items     = (const int*)d_in[0];
    const int*   actions   = (const int*)d_in[1];
    const float* WihT      = (const float*)d_in[2];
    const float* Whh       = (const float*)d_in[3];
    const float* b_lstm    = (const float*)d_in[4];
    const float* trans_emb = (const float*)d_in[5];
    const float* Wq        = (const float*)d_in[6];
    const float* bq        = (const float*)d_in[7];

    char*  ws    = (char*)d_ws;
    int*   flags = (int*)ws;                   // 8192 B
    float* accum = (float*)(ws + 8192);        // 8 B
    float* h_buf = (float*)(ws + 12288);       // 131072 B

    hipMemsetAsync(d_ws, 0, 12288 + 64 * 2 * 256 * 4, stream);

    lstm_main<<<dim3(64), dim3(512), 0, stream>>>(
        items, actions, WihT, Whh, b_lstm, trans_emb, Wq, bq, flags, h_buf, accum);
    finalize_k<<<dim3(1), dim3(1), 0, stream>>>(accum, (float*)d_out);
}